// Round 2
// baseline (1292.166 us; speedup 1.0000x reference)
//
#include <hip/hip_runtime.h>
#include <cstdint>
#include <cstddef>

namespace {

constexpr int kN   = 100000;   // nodes per type (N_REQ == N_CODE)
constexpr int kE   = 500000;   // edges per direction
constexpr int kEL  = 200000;   // label edges
constexpr int kC   = 256;      // channels
constexpr int kH   = 8;        // heads
constexpr float kNegSlope = 0.2f;
constexpr float kBnEps    = 1e-5f;

typedef float  f32x4  __attribute__((ext_vector_type(4)));
typedef __bf16 bf16x8 __attribute__((ext_vector_type(8)));

__device__ inline unsigned short bf16_rtn(float x) {
  unsigned u = __builtin_bit_cast(unsigned, x);
  unsigned r = (u + 0x7fffu + ((u >> 16) & 1u)) >> 16;
  return (unsigned short)r;
}
__device__ inline float bf16_f(unsigned short h) {
  unsigned u = ((unsigned)h) << 16;
  return __builtin_bit_cast(float, u);
}

// ------------- zero-fill (graph-capture-safe replacement for hipMemsetAsync) ---
__global__ void zero_kernel(int* __restrict__ p, int n) {
  const int i = blockIdx.x * 256 + threadIdx.x;
  if (i < n) p[i] = 0;
}

// ------------- GEMM: H[M,256] = X[M,256] @ W[256,256]^T + b -------------
// split-bf16: X = Xhi+Xlo, W = Whi+Wlo; H ~= Xhi*Whi + Xhi*Wlo + Xlo*Whi
constexpr int BM = 128, BN = 128, BK = 32, LDA = 40;  // LDA padded (2-way LDS alias only)

__global__ __launch_bounds__(256) void gemm_kernel(
    const float* __restrict__ X, const float* __restrict__ W,
    const float* __restrict__ bias, float* __restrict__ H, int M) {
  __shared__ unsigned short sAhi[BM * LDA];
  __shared__ unsigned short sAlo[BM * LDA];
  __shared__ unsigned short sBhi[BN * LDA];
  __shared__ unsigned short sBlo[BN * LDA];

  const int tid  = threadIdx.x;
  const int m0   = blockIdx.y * BM;
  const int n0   = blockIdx.x * BN;
  const int w    = tid >> 6, lane = tid & 63, l16 = lane & 15, quad = lane >> 4;
  const int wm   = (w >> 1) * 64, wn = (w & 1) * 64;
  const int rbase = tid >> 3;       // 0..31
  const int cb    = (tid & 7) * 4;  // 0..28

  f32x4 acc[4][4] = {};

  for (int kt = 0; kt < kC / BK; ++kt) {
    const int k0 = kt * BK;
    __syncthreads();
    // stage A tile (fp32 -> hi/lo bf16)
    for (int rr = rbase; rr < BM; rr += 32) {
      const int gm = m0 + rr;
      float4 v = make_float4(0.f, 0.f, 0.f, 0.f);
      if (gm < M) v = *(const float4*)&X[(size_t)gm * kC + k0 + cb];
      unsigned short h0 = bf16_rtn(v.x), h1 = bf16_rtn(v.y),
                     h2 = bf16_rtn(v.z), h3 = bf16_rtn(v.w);
      ushort4 hv = make_ushort4(h0, h1, h2, h3);
      ushort4 lv = make_ushort4(bf16_rtn(v.x - bf16_f(h0)),
                                bf16_rtn(v.y - bf16_f(h1)),
                                bf16_rtn(v.z - bf16_f(h2)),
                                bf16_rtn(v.w - bf16_f(h3)));
      *(ushort4*)&sAhi[rr * LDA + cb] = hv;
      *(ushort4*)&sAlo[rr * LDA + cb] = lv;
    }
    // stage B tile (W rows n0..n0+127)
    for (int rr = rbase; rr < BN; rr += 32) {
      const int gn = n0 + rr;
      const float4 v = *(const float4*)&W[(size_t)gn * kC + k0 + cb];
      unsigned short h0 = bf16_rtn(v.x), h1 = bf16_rtn(v.y),
                     h2 = bf16_rtn(v.z), h3 = bf16_rtn(v.w);
      ushort4 hv = make_ushort4(h0, h1, h2, h3);
      ushort4 lv = make_ushort4(bf16_rtn(v.x - bf16_f(h0)),
                                bf16_rtn(v.y - bf16_f(h1)),
                                bf16_rtn(v.z - bf16_f(h2)),
                                bf16_rtn(v.w - bf16_f(h3)));
      *(ushort4*)&sBhi[rr * LDA + cb] = hv;
      *(ushort4*)&sBlo[rr * LDA + cb] = lv;
    }
    __syncthreads();

    bf16x8 ah[4], al[4], bh[4], bl[4];
    for (int mi = 0; mi < 4; ++mi) {
      const int row = wm + mi * 16 + l16;
      ah[mi] = *(const bf16x8*)&sAhi[row * LDA + quad * 8];
      al[mi] = *(const bf16x8*)&sAlo[row * LDA + quad * 8];
    }
    for (int ni = 0; ni < 4; ++ni) {
      const int row = wn + ni * 16 + l16;
      bh[ni] = *(const bf16x8*)&sBhi[row * LDA + quad * 8];
      bl[ni] = *(const bf16x8*)&sBlo[row * LDA + quad * 8];
    }
    for (int mi = 0; mi < 4; ++mi)
      for (int ni = 0; ni < 4; ++ni) {
        acc[mi][ni] = __builtin_amdgcn_mfma_f32_16x16x32_bf16(ah[mi], bh[ni], acc[mi][ni], 0, 0, 0);
        acc[mi][ni] = __builtin_amdgcn_mfma_f32_16x16x32_bf16(ah[mi], bl[ni], acc[mi][ni], 0, 0, 0);
        acc[mi][ni] = __builtin_amdgcn_mfma_f32_16x16x32_bf16(al[mi], bh[ni], acc[mi][ni], 0, 0, 0);
      }
  }

  // epilogue: D[row=quad*4+r][col=l16] per 16x16 tile, + bias
  for (int ni = 0; ni < 4; ++ni) {
    const int col = n0 + wn + ni * 16 + l16;
    const float bc = bias[col];
    for (int mi = 0; mi < 4; ++mi) {
      const int gm0 = m0 + wm + mi * 16 + quad * 4;
      for (int r = 0; r < 4; ++r) {
        const int gm = gm0 + r;
        if (gm < M) H[(size_t)gm * kC + col] = acc[mi][ni][r] + bc;
      }
    }
  }
}

// ------------- per-node attention scalars: a[n,h] = <h[n,h,:], att[h,:]> -------------
__global__ __launch_bounds__(256) void avec_kernel(
    const float* __restrict__ h, const float* __restrict__ attA,
    const float* __restrict__ attB, float* __restrict__ outA,
    float* __restrict__ outB, int N) {
  const int n = blockIdx.x * 4 + (threadIdx.x >> 6);
  if (n >= N) return;
  const int L = threadIdx.x & 63;
  const float4 hv = *(const float4*)&h[(size_t)n * kC + 4 * L];
  const float4 a  = *(const float4*)&attA[4 * L];   // flat att idx == channel idx
  const float4 b  = *(const float4*)&attB[4 * L];
  float pa = hv.x * a.x + hv.y * a.y + hv.z * a.z + hv.w * a.w;
  float pb = hv.x * b.x + hv.y * b.y + hv.z * b.z + hv.w * b.w;
  for (int m = 1; m < 8; m <<= 1) {
    pa += __shfl_xor(pa, m);
    pb += __shfl_xor(pb, m);
  }
  if ((L & 7) == 0) {
    outA[n * kH + (L >> 3)] = pa;
    outB[n * kH + (L >> 3)] = pb;
  }
}

// ------------- CSR build -------------
__global__ void count_kernel(const int* __restrict__ dst, int E, int* __restrict__ cnt) {
  const int e = blockIdx.x * 256 + threadIdx.x;
  if (e < E) atomicAdd(&cnt[dst[e]], 1);
}

__global__ void scan1_kernel(const int* __restrict__ cnt, int N,
                             int* __restrict__ off, int* __restrict__ part) {
  __shared__ int s[256];
  const int t = threadIdx.x;
  const int i = blockIdx.x * 256 + t;
  const int v = (i < N) ? cnt[i] : 0;
  s[t] = v;
  __syncthreads();
  for (int o = 1; o < 256; o <<= 1) {
    const int x = (t >= o) ? s[t - o] : 0;
    __syncthreads();
    s[t] += x;
    __syncthreads();
  }
  if (i < N) off[i] = s[t] - v;            // exclusive within block
  if (t == 255) part[blockIdx.x] = s[255]; // block sum
}

__global__ void scan2_kernel(int* __restrict__ part, int NB) {  // one block, 512 threads
  __shared__ int s[512];
  const int t = threadIdx.x;
  const int v = (t < NB) ? part[t] : 0;
  s[t] = v;
  __syncthreads();
  for (int o = 1; o < 512; o <<= 1) {
    const int x = (t >= o) ? s[t - o] : 0;
    __syncthreads();
    s[t] += x;
    __syncthreads();
  }
  if (t < NB) part[t] = s[t] - v;  // exclusive
}

__global__ void scan3_kernel(int* __restrict__ off, int* __restrict__ cur,
                             const int* __restrict__ part, int N) {
  const int i = blockIdx.x * 256 + threadIdx.x;
  if (i < N) {
    const int v = off[i] + part[blockIdx.x];
    off[i] = v;
    cur[i] = v;
  }
}

__global__ void scatter_kernel(const int* __restrict__ dst, int E,
                               int* __restrict__ cur, int* __restrict__ perm) {
  const int e = blockIdx.x * 256 + threadIdx.x;
  if (e < E) {
    const int p = atomicAdd(&cur[dst[e]], 1);
    perm[p] = e;
  }
}

// ------------- fused segment-softmax + weighted aggregate + relu -------------
// out[d,:] = relu( (sum_e exp(leaky(aS[s_e]+aD[d])) * h_src[s_e,:]) / (sum_e exp + 1e-16) )
__global__ __launch_bounds__(256) void aggregate_kernel(
    const float* __restrict__ hsrc, const float* __restrict__ aS,
    const float* __restrict__ aD, const int* __restrict__ src,
    const int* __restrict__ off, const int* __restrict__ cnt,
    const int* __restrict__ perm, float* __restrict__ out, int Ndst) {
  const int d = blockIdx.x * 4 + (threadIdx.x >> 6);
  if (d >= Ndst) return;
  const int L  = threadIdx.x & 63;
  const int hd = L >> 3;  // lane's 4 channels all live in head L>>3
  const float ad = aD[d * kH + hd];
  const int o = off[d], c = cnt[d];
  float4 acc = make_float4(0.f, 0.f, 0.f, 0.f);
  float se = 0.f;
  for (int i = 0; i < c; ++i) {
    const int e = perm[o + i];
    const int s = src[e];
    float t = aS[s * kH + hd] + ad;
    t = t > 0.f ? t : kNegSlope * t;
    const float wgt = __expf(t);
    se += wgt;
    const float4 hv = *(const float4*)&hsrc[(size_t)s * kC + 4 * L];
    acc.x += wgt * hv.x;
    acc.y += wgt * hv.y;
    acc.z += wgt * hv.z;
    acc.w += wgt * hv.w;
  }
  const float inv = 1.f / (se + 1e-16f);
  float4 r;
  r.x = fmaxf(acc.x * inv, 0.f);
  r.y = fmaxf(acc.y * inv, 0.f);
  r.z = fmaxf(acc.z * inv, 0.f);
  r.w = fmaxf(acc.w * inv, 0.f);
  *(float4*)&out[(size_t)d * kC + 4 * L] = r;
}

// ------------- BatchNorm stats (biased var) -------------
constexpr int kBnRows = 391;  // 256 blocks * 391 >= 100000
__global__ __launch_bounds__(256) void bn_stats_kernel(
    const float* __restrict__ x, int N, float* __restrict__ sum,
    float* __restrict__ sumsq) {
  const int c  = threadIdx.x;
  const int r0 = blockIdx.x * kBnRows;
  const int r1 = min(r0 + kBnRows, N);
  float s = 0.f, s2 = 0.f;
  for (int r = r0; r < r1; ++r) {
    const float v = x[(size_t)r * kC + c];
    s += v;
    s2 += v * v;
  }
  atomicAdd(&sum[c], s);
  atomicAdd(&sumsq[c], s2);
}

// stats: [sum_r | sumsq_r | sum_c | sumsq_c], sb out: [scale_r | bias_r | scale_c | bias_c]
__global__ void bn_final_kernel(const float* __restrict__ stats,
                                const float* __restrict__ gamma,
                                const float* __restrict__ beta,
                                float* __restrict__ sb) {
  const int c = threadIdx.x;
  for (int t = 0; t < 2; ++t) {
    const float mu  = stats[t * 512 + c] * (1.f / kN);
    const float var = stats[t * 512 + 256 + c] * (1.f / kN) - mu * mu;
    const float sc  = gamma[c] * rsqrtf(var + kBnEps);
    sb[t * 512 + c]       = sc;
    sb[t * 512 + 256 + c] = beta[c] - mu * sc;
  }
}

// ------------- edge classifier: sigmoid(<z_req[i], z_code[j]>) with fused BN -------------
__global__ __launch_bounds__(256) void classify_kernel(
    const float* __restrict__ zr, const float* __restrict__ zc,
    const int* __restrict__ ei, const int* __restrict__ ej,
    const float* __restrict__ sb, float* __restrict__ y, int EL) {
  const int e = blockIdx.x * 4 + (threadIdx.x >> 6);
  if (e >= EL) return;
  const int L = threadIdx.x & 63;
  const int i = ei[e], j = ej[e];
  const float4 a  = *(const float4*)&zr[(size_t)i * kC + 4 * L];
  const float4 b  = *(const float4*)&zc[(size_t)j * kC + 4 * L];
  const float4 sr = *(const float4*)&sb[4 * L];
  const float4 br = *(const float4*)&sb[256 + 4 * L];
  const float4 sc = *(const float4*)&sb[512 + 4 * L];
  const float4 bc = *(const float4*)&sb[768 + 4 * L];
  float p = (a.x * sr.x + br.x) * (b.x * sc.x + bc.x) +
            (a.y * sr.y + br.y) * (b.y * sc.y + bc.y) +
            (a.z * sr.z + br.z) * (b.z * sc.z + bc.z) +
            (a.w * sr.w + br.w) * (b.w * sc.w + bc.w);
  for (int m = 1; m < 64; m <<= 1) p += __shfl_xor(p, m);
  if (L == 0) y[e] = 1.f / (1.f + __expf(-p));
}

}  // namespace

extern "C" void kernel_launch(void* const* d_in, const int* in_sizes, int n_in,
                              void* d_out, int out_size, void* d_ws, size_t ws_size,
                              hipStream_t stream) {
  (void)in_sizes; (void)n_in; (void)out_size; (void)ws_size;
  const float* x_req      = (const float*)d_in[0];
  const float* x_code     = (const float*)d_in[1];
  const int*   ei_rc      = (const int*)d_in[2];   // [src(E) | dst(E)] req->code
  const int*   ei_cr      = (const int*)d_in[3];   // [src(E) | dst(E)] code->req
  const int*   el         = (const int*)d_in[4];   // [req(EL) | code(EL)]
  const float* W_req      = (const float*)d_in[5];
  const float* b_req      = (const float*)d_in[6];
  const float* W_code     = (const float*)d_in[7];
  const float* b_code     = (const float*)d_in[8];
  const float* att_src_rc = (const float*)d_in[9];
  const float* att_dst_rc = (const float*)d_in[10];
  const float* att_src_cr = (const float*)d_in[11];
  const float* att_dst_cr = (const float*)d_in[12];
  // d_in[13..15] = k_W, k_b, q : semantic attention over ONE metapath == identity -> unused
  const float* gamma      = (const float*)d_in[16];
  const float* beta       = (const float*)d_in[17];
  float* y = (float*)d_out;

  // ---- workspace layout (~326 MB peak; out_req ALIASES h_req's buffer) ----
  char* p = (char*)d_ws;
  auto alloc = [&](size_t bytes) {
    char* r = p;
    p += (bytes + 1023) & ~(size_t)1023;
    return r;
  };
  float* h_req    = (float*)alloc((size_t)kN * kC * 4);  // later reused as out_req
  float* h_code   = (float*)alloc((size_t)kN * kC * 4);
  float* out_code = (float*)alloc((size_t)kN * kC * 4);
  float* out_req  = h_req;  // alias: h_req is dead after the rc aggregation
  float* a_src_rc = (float*)alloc((size_t)kN * kH * 4);
  float* a_dst_rc = (float*)alloc((size_t)kN * kH * 4);
  float* a_src_cr = (float*)alloc((size_t)kN * kH * 4);
  float* a_dst_cr = (float*)alloc((size_t)kN * kH * 4);
  int* cnt_rc  = (int*)alloc((size_t)kN * 4);
  int* off_rc  = (int*)alloc((size_t)kN * 4);
  int* cur_rc  = (int*)alloc((size_t)kN * 4);
  int* perm_rc = (int*)alloc((size_t)kE * 4);
  int* cnt_cr  = (int*)alloc((size_t)kN * 4);
  int* off_cr  = (int*)alloc((size_t)kN * 4);
  int* cur_cr  = (int*)alloc((size_t)kN * 4);
  int* perm_cr = (int*)alloc((size_t)kE * 4);
  int*   part  = (int*)alloc(512 * 4);
  float* stats = (float*)alloc(1024 * 4);  // [sum_r|sumsq_r|sum_c|sumsq_c]
  float* sb    = (float*)alloc(1024 * 4);  // [scale_r|bias_r|scale_c|bias_c]

  const int nScanB = (kN + 255) / 256;  // 391

  // zero-init (kernel, not hipMemsetAsync, for graph-capture safety)
  zero_kernel<<<nScanB, 256, 0, stream>>>(cnt_rc, kN);
  zero_kernel<<<nScanB, 256, 0, stream>>>(cnt_cr, kN);
  zero_kernel<<<4, 256, 0, stream>>>((int*)stats, 1024);

  // projections
  dim3 ggrid(kC / BN, (kN + BM - 1) / BM);
  gemm_kernel<<<ggrid, 256, 0, stream>>>(x_req, W_req, b_req, h_req, kN);
  gemm_kernel<<<ggrid, 256, 0, stream>>>(x_code, W_code, b_code, h_code, kN);

  // attention scalars: req is src in rc, dst in cr; code is dst in rc, src in cr
  avec_kernel<<<(kN + 3) / 4, 256, 0, stream>>>(h_req, att_src_rc, att_dst_cr,
                                                a_src_rc, a_dst_cr, kN);
  avec_kernel<<<(kN + 3) / 4, 256, 0, stream>>>(h_code, att_src_cr, att_dst_rc,
                                                a_src_cr, a_dst_rc, kN);

  // CSR build (dst-sorted edge permutation per direction)
  const int* dst_rc = ei_rc + kE;
  const int* dst_cr = ei_cr + kE;
  count_kernel<<<(kE + 255) / 256, 256, 0, stream>>>(dst_rc, kE, cnt_rc);
  count_kernel<<<(kE + 255) / 256, 256, 0, stream>>>(dst_cr, kE, cnt_cr);
  scan1_kernel<<<nScanB, 256, 0, stream>>>(cnt_rc, kN, off_rc, part);
  scan2_kernel<<<1, 512, 0, stream>>>(part, nScanB);
  scan3_kernel<<<nScanB, 256, 0, stream>>>(off_rc, cur_rc, part, kN);
  scan1_kernel<<<nScanB, 256, 0, stream>>>(cnt_cr, kN, off_cr, part);
  scan2_kernel<<<1, 512, 0, stream>>>(part, nScanB);
  scan3_kernel<<<nScanB, 256, 0, stream>>>(off_cr, cur_cr, part, kN);
  scatter_kernel<<<(kE + 255) / 256, 256, 0, stream>>>(dst_rc, kE, cur_rc, perm_rc);
  scatter_kernel<<<(kE + 255) / 256, 256, 0, stream>>>(dst_cr, kE, cur_cr, perm_cr);

  // fused attention softmax + aggregation + relu
  // rc first (consumes h_req) ...
  aggregate_kernel<<<(kN + 3) / 4, 256, 0, stream>>>(
      h_req, a_src_rc, a_dst_rc, ei_rc, off_rc, cnt_rc, perm_rc, out_code, kN);
  // ... then cr may overwrite h_req's buffer with out_req (reads only h_code)
  aggregate_kernel<<<(kN + 3) / 4, 256, 0, stream>>>(
      h_code, a_src_cr, a_dst_cr, ei_cr, off_cr, cnt_cr, perm_cr, out_req, kN);

  // BatchNorm (training-mode batch stats), fused into classifier via scale/bias
  bn_stats_kernel<<<256, 256, 0, stream>>>(out_req, kN, stats, stats + 256);
  bn_stats_kernel<<<256, 256, 0, stream>>>(out_code, kN, stats + 512, stats + 768);
  bn_final_kernel<<<1, 256, 0, stream>>>(stats, gamma, beta, sb);

  // edge dot-product classifier
  classify_kernel<<<(kEL + 3) / 4, 256, 0, stream>>>(
      out_req, out_code, el, el + kEL, sb, y, kEL);
}

// Round 3
// 1135.077 us; speedup vs baseline: 1.1384x; 1.1384x over previous
//
#include <hip/hip_runtime.h>
#include <cstdint>
#include <cstddef>

namespace {

constexpr int kN    = 100000;  // nodes per type (N_REQ == N_CODE)
constexpr int kNpad = 100096;  // 782*128, GEMM tile-padded row count
constexpr int kE    = 500000;  // edges per direction
constexpr int kEL   = 200000;  // label edges
constexpr int kC    = 256;     // channels
constexpr int kH    = 8;       // heads
constexpr float kNegSlope = 0.2f;
constexpr float kBnEps    = 1e-5f;

typedef float    f32x4  __attribute__((ext_vector_type(4)));
typedef __bf16   bf16x8 __attribute__((ext_vector_type(8)));
typedef _Float16 h4     __attribute__((ext_vector_type(4)));

__device__ inline unsigned short bf16_rtn(float x) {
  unsigned u = __builtin_bit_cast(unsigned, x);
  unsigned r = (u + 0x7fffu + ((u >> 16) & 1u)) >> 16;
  return (unsigned short)r;
}
__device__ inline float bf16_f(unsigned short h) {
  unsigned u = ((unsigned)h) << 16;
  return __builtin_bit_cast(float, u);
}

// async global->LDS, 16 B per lane; lds base must be wave-uniform (lane*16 added by HW)
__device__ inline void async_copy16(unsigned short* lds, const unsigned short* g) {
  __builtin_amdgcn_global_load_lds(
      (const __attribute__((address_space(1))) unsigned int*)g,
      (__attribute__((address_space(3))) unsigned int*)lds, 16, 0, 0);
}

// ------------- zero-fill (graph-capture-safe) -------------
__global__ void zero_kernel(int* __restrict__ p, int n) {
  const int i = blockIdx.x * 256 + threadIdx.x;
  if (i < n) p[i] = 0;
}

// ------------- fp32 -> split bf16 (hi/lo) conversion, streaming -------------
__global__ __launch_bounds__(256) void cvt_kernel(
    const float* __restrict__ in, unsigned short* __restrict__ hi,
    unsigned short* __restrict__ lo, int n4) {
  const int i = blockIdx.x * 256 + threadIdx.x;
  if (i >= n4) return;
  const float4 v = ((const float4*)in)[i];
  const unsigned short h0 = bf16_rtn(v.x), h1 = bf16_rtn(v.y),
                       h2 = bf16_rtn(v.z), h3 = bf16_rtn(v.w);
  ((ushort4*)hi)[i] = make_ushort4(h0, h1, h2, h3);
  ((ushort4*)lo)[i] = make_ushort4(bf16_rtn(v.x - bf16_f(h0)),
                                   bf16_rtn(v.y - bf16_f(h1)),
                                   bf16_rtn(v.z - bf16_f(h2)),
                                   bf16_rtn(v.w - bf16_f(h3)));
}

// ------------- GEMM (m97 structure): H[M,256] = X @ W^T + b, fp16 out -------------
// split-bf16: H ~= Xhi*Whi + Xhi*Wlo + Xlo*Whi  (3 MFMA passes)
// LDS tiles 128x32 bf16 row-major, staged via global_load_lds dwordx4 (1 tile/wave).
__global__ __launch_bounds__(256) void gemm_kernel(
    const unsigned short* __restrict__ Ahi, const unsigned short* __restrict__ Alo,
    const unsigned short* __restrict__ Bhi, const unsigned short* __restrict__ Blo,
    const float* __restrict__ bias, _Float16* __restrict__ H, int M) {
  __shared__ unsigned short sAhi[128 * 32];
  __shared__ unsigned short sAlo[128 * 32];
  __shared__ unsigned short sBhi[128 * 32];
  __shared__ unsigned short sBlo[128 * 32];

  const int tid  = threadIdx.x;
  const int m0   = blockIdx.y * 128;
  const int n0   = blockIdx.x * 128;
  const int w    = tid >> 6, lane = tid & 63, l16 = lane & 15, quad = lane >> 4;
  const int wm   = (w >> 1) * 64, wn = (w & 1) * 64;

  // wave w stages tile w: 0=Ahi 1=Alo 2=Bhi 3=Blo
  const unsigned short* gsrc = (w == 0) ? Ahi : (w == 1) ? Alo : (w == 2) ? Bhi : Blo;
  unsigned short* lds        = (w == 0) ? sAhi : (w == 1) ? sAlo : (w == 2) ? sBhi : sBlo;
  const int row0 = (w < 2) ? m0 : n0;
  // lane L covers (row = 16j + L/4, 16B chunk L%4) of chunk j
  const size_t gbase = (size_t)(row0 + (lane >> 2)) * kC + (lane & 3) * 8;

  f32x4 acc[4][4] = {};

  for (int kt = 0; kt < kC / 32; ++kt) {
    const int k0 = kt * 32;
    __syncthreads();  // prior ds_reads done before overwrite
#pragma unroll
    for (int j = 0; j < 8; ++j)
      async_copy16(lds + j * 512, gsrc + gbase + (size_t)j * 16 * kC + k0);
    __syncthreads();  // drains vmcnt (global_load_lds) before ds_read

    bf16x8 ah[4], al[4], bh[4], bl[4];
#pragma unroll
    for (int mi = 0; mi < 4; ++mi) {
      const int row = wm + mi * 16 + l16;
      ah[mi] = *(const bf16x8*)&sAhi[row * 32 + quad * 8];
      al[mi] = *(const bf16x8*)&sAlo[row * 32 + quad * 8];
    }
#pragma unroll
    for (int ni = 0; ni < 4; ++ni) {
      const int row = wn + ni * 16 + l16;
      bh[ni] = *(const bf16x8*)&sBhi[row * 32 + quad * 8];
      bl[ni] = *(const bf16x8*)&sBlo[row * 32 + quad * 8];
    }
#pragma unroll
    for (int mi = 0; mi < 4; ++mi)
#pragma unroll
      for (int ni = 0; ni < 4; ++ni) {
        acc[mi][ni] = __builtin_amdgcn_mfma_f32_16x16x32_bf16(ah[mi], bh[ni], acc[mi][ni], 0, 0, 0);
        acc[mi][ni] = __builtin_amdgcn_mfma_f32_16x16x32_bf16(ah[mi], bl[ni], acc[mi][ni], 0, 0, 0);
        acc[mi][ni] = __builtin_amdgcn_mfma_f32_16x16x32_bf16(al[mi], bh[ni], acc[mi][ni], 0, 0, 0);
      }
  }

  // epilogue: D[row=quad*4+r][col=l16] per 16x16 tile; +bias, fp16 store
#pragma unroll
  for (int ni = 0; ni < 4; ++ni) {
    const int col = n0 + wn + ni * 16 + l16;
    const float bc = bias[col];
#pragma unroll
    for (int mi = 0; mi < 4; ++mi) {
      const int gm0 = m0 + wm + mi * 16 + quad * 4;
#pragma unroll
      for (int r = 0; r < 4; ++r) {
        const int gm = gm0 + r;
        if (gm < M) H[(size_t)gm * kC + col] = (_Float16)(acc[mi][ni][r] + bc);
      }
    }
  }
}

// ------------- per-node attention scalars: a[n,h] = <h[n,h,:], att[h,:]> -------------
__global__ __launch_bounds__(256) void avec_kernel(
    const _Float16* __restrict__ h, const float* __restrict__ attA,
    const float* __restrict__ attB, float* __restrict__ outA,
    float* __restrict__ outB, int N) {
  const int n = blockIdx.x * 4 + (threadIdx.x >> 6);
  if (n >= N) return;
  const int L = threadIdx.x & 63;
  const h4 hv = *(const h4*)&h[(size_t)n * kC + 4 * L];
  const float4 a = *(const float4*)&attA[4 * L];
  const float4 b = *(const float4*)&attB[4 * L];
  const float hx = (float)hv.x, hy = (float)hv.y, hz = (float)hv.z, hw = (float)hv.w;
  float pa = hx * a.x + hy * a.y + hz * a.z + hw * a.w;
  float pb = hx * b.x + hy * b.y + hz * b.z + hw * b.w;
  for (int m = 1; m < 8; m <<= 1) {
    pa += __shfl_xor(pa, m);
    pb += __shfl_xor(pb, m);
  }
  if ((L & 7) == 0) {
    outA[n * kH + (L >> 3)] = pa;
    outB[n * kH + (L >> 3)] = pb;
  }
}

// ------------- CSR build -------------
__global__ void count_kernel(const int* __restrict__ dst, int E, int* __restrict__ cnt) {
  const int e = blockIdx.x * 256 + threadIdx.x;
  if (e < E) atomicAdd(&cnt[dst[e]], 1);
}

__global__ void scan1_kernel(const int* __restrict__ cnt, int N,
                             int* __restrict__ off, int* __restrict__ part) {
  __shared__ int s[256];
  const int t = threadIdx.x;
  const int i = blockIdx.x * 256 + t;
  const int v = (i < N) ? cnt[i] : 0;
  s[t] = v;
  __syncthreads();
  for (int o = 1; o < 256; o <<= 1) {
    const int x = (t >= o) ? s[t - o] : 0;
    __syncthreads();
    s[t] += x;
    __syncthreads();
  }
  if (i < N) off[i] = s[t] - v;
  if (t == 255) part[blockIdx.x] = s[255];
}

__global__ void scan2_kernel(int* __restrict__ part, int NB) {  // one block, 512 thr
  __shared__ int s[512];
  const int t = threadIdx.x;
  const int v = (t < NB) ? part[t] : 0;
  s[t] = v;
  __syncthreads();
  for (int o = 1; o < 512; o <<= 1) {
    const int x = (t >= o) ? s[t - o] : 0;
    __syncthreads();
    s[t] += x;
    __syncthreads();
  }
  if (t < NB) part[t] = s[t] - v;
}

__global__ void scan3_kernel(int* __restrict__ off, int* __restrict__ cur,
                             const int* __restrict__ part, int N) {
  const int i = blockIdx.x * 256 + threadIdx.x;
  if (i < N) {
    const int v = off[i] + part[blockIdx.x];
    off[i] = v;
    cur[i] = v;
  }
}

__global__ void scatter_kernel(const int* __restrict__ dst, int E,
                               int* __restrict__ cur, int* __restrict__ perm) {
  const int e = blockIdx.x * 256 + threadIdx.x;
  if (e < E) {
    const int p = atomicAdd(&cur[dst[e]], 1);
    perm[p] = e;
  }
}

// ------------- fused segment-softmax + weighted aggregate + relu -------------
__global__ __launch_bounds__(256) void aggregate_kernel(
    const _Float16* __restrict__ hsrc, const float* __restrict__ aS,
    const float* __restrict__ aD, const int* __restrict__ src,
    const int* __restrict__ off, const int* __restrict__ cnt,
    const int* __restrict__ perm, float* __restrict__ out, int Ndst) {
  const int d = blockIdx.x * 4 + (threadIdx.x >> 6);
  if (d >= Ndst) return;
  const int L  = threadIdx.x & 63;
  const int hd = L >> 3;  // lane's 4 channels all in head L>>3
  const float ad = aD[d * kH + hd];
  const int o = off[d], c = cnt[d];
  float4 acc = make_float4(0.f, 0.f, 0.f, 0.f);
  float se = 0.f;
  for (int i = 0; i < c; ++i) {
    const int e = perm[o + i];
    const int s = src[e];
    float t = aS[s * kH + hd] + ad;
    t = t > 0.f ? t : kNegSlope * t;
    const float wgt = __expf(t);
    se += wgt;
    const h4 hv = *(const h4*)&hsrc[(size_t)s * kC + 4 * L];
    acc.x += wgt * (float)hv.x;
    acc.y += wgt * (float)hv.y;
    acc.z += wgt * (float)hv.z;
    acc.w += wgt * (float)hv.w;
  }
  const float inv = 1.f / (se + 1e-16f);
  float4 r;
  r.x = fmaxf(acc.x * inv, 0.f);
  r.y = fmaxf(acc.y * inv, 0.f);
  r.z = fmaxf(acc.z * inv, 0.f);
  r.w = fmaxf(acc.w * inv, 0.f);
  *(float4*)&out[(size_t)d * kC + 4 * L] = r;
}

// ------------- BatchNorm stats (biased var) -------------
constexpr int kBnRows = 391;
__global__ __launch_bounds__(256) void bn_stats_kernel(
    const float* __restrict__ x, int N, float* __restrict__ sum,
    float* __restrict__ sumsq) {
  const int c  = threadIdx.x;
  const int r0 = blockIdx.x * kBnRows;
  const int r1 = min(r0 + kBnRows, N);
  float s = 0.f, s2 = 0.f;
  for (int r = r0; r < r1; ++r) {
    const float v = x[(size_t)r * kC + c];
    s += v;
    s2 += v * v;
  }
  atomicAdd(&sum[c], s);
  atomicAdd(&sumsq[c], s2);
}

__global__ void bn_final_kernel(const float* __restrict__ stats,
                                const float* __restrict__ gamma,
                                const float* __restrict__ beta,
                                float* __restrict__ sb) {
  const int c = threadIdx.x;
  for (int t = 0; t < 2; ++t) {
    const float mu  = stats[t * 512 + c] * (1.f / kN);
    const float var = stats[t * 512 + 256 + c] * (1.f / kN) - mu * mu;
    const float sc  = gamma[c] * rsqrtf(var + kBnEps);
    sb[t * 512 + c]       = sc;
    sb[t * 512 + 256 + c] = beta[c] - mu * sc;
  }
}

// ------------- edge classifier: sigmoid(<z_req[i], z_code[j]>), BN fused -------------
__global__ __launch_bounds__(256) void classify_kernel(
    const float* __restrict__ zr, const float* __restrict__ zc,
    const int* __restrict__ ei, const int* __restrict__ ej,
    const float* __restrict__ sb, float* __restrict__ y, int EL) {
  const int e = blockIdx.x * 4 + (threadIdx.x >> 6);
  if (e >= EL) return;
  const int L = threadIdx.x & 63;
  const int i = ei[e], j = ej[e];
  const float4 a  = *(const float4*)&zr[(size_t)i * kC + 4 * L];
  const float4 b  = *(const float4*)&zc[(size_t)j * kC + 4 * L];
  const float4 sr = *(const float4*)&sb[4 * L];
  const float4 br = *(const float4*)&sb[256 + 4 * L];
  const float4 sc = *(const float4*)&sb[512 + 4 * L];
  const float4 bc = *(const float4*)&sb[768 + 4 * L];
  float p = (a.x * sr.x + br.x) * (b.x * sc.x + bc.x) +
            (a.y * sr.y + br.y) * (b.y * sc.y + bc.y) +
            (a.z * sr.z + br.z) * (b.z * sc.z + bc.z) +
            (a.w * sr.w + br.w) * (b.w * sc.w + bc.w);
  for (int m = 1; m < 64; m <<= 1) p += __shfl_xor(p, m);
  if (L == 0) y[e] = 1.f / (1.f + __expf(-p));
}

}  // namespace

extern "C" void kernel_launch(void* const* d_in, const int* in_sizes, int n_in,
                              void* d_out, int out_size, void* d_ws, size_t ws_size,
                              hipStream_t stream) {
  (void)in_sizes; (void)n_in; (void)out_size; (void)ws_size;
  const float* x_req      = (const float*)d_in[0];
  const float* x_code     = (const float*)d_in[1];
  const int*   ei_rc      = (const int*)d_in[2];   // [src(E) | dst(E)] req -> code
  const int*   ei_cr      = (const int*)d_in[3];   // [src(E) | dst(E)] code -> req
  const int*   el         = (const int*)d_in[4];   // [req(EL) | code(EL)]
  const float* W_req      = (const float*)d_in[5];
  const float* b_req      = (const float*)d_in[6];
  const float* W_code     = (const float*)d_in[7];
  const float* b_code     = (const float*)d_in[8];
  const float* att_src_rc = (const float*)d_in[9];
  const float* att_dst_rc = (const float*)d_in[10];
  const float* att_src_cr = (const float*)d_in[11];
  const float* att_dst_cr = (const float*)d_in[12];
  // d_in[13..15] = k_W, k_b, q : semantic attn over ONE metapath == identity -> unused
  const float* gamma      = (const float*)d_in[16];
  const float* beta       = (const float*)d_in[17];
  float* y = (float*)d_out;

  // ---- workspace (~325 MB peak) ----
  char* p = (char*)d_ws;
  auto alloc = [&](size_t bytes) {
    char* r = p;
    p += (bytes + 1023) & ~(size_t)1023;
    return r;
  };
  // X split-bf16 region, reused per node type; reused again as out_code after GEMMs
  unsigned short* Xhi = (unsigned short*)alloc((size_t)kNpad * kC * 2);  // 51.25 MB
  unsigned short* Xlo = (unsigned short*)alloc((size_t)kNpad * kC * 2);  // 51.25 MB
  float* out_code = (float*)Xhi;  // alias: X dead after both GEMMs (needs 102.4 MB)
  _Float16* h_req  = (_Float16*)alloc((size_t)kN * kC * 2);  // 51.2 MB
  _Float16* h_code = (_Float16*)alloc((size_t)kN * kC * 2);  // 51.2 MB
  float* out_req   = (float*)alloc((size_t)kN * kC * 4);     // 102.4 MB
  unsigned short* Whi_r = (unsigned short*)alloc((size_t)kC * kC * 2);
  unsigned short* Wlo_r = (unsigned short*)alloc((size_t)kC * kC * 2);
  unsigned short* Whi_c = (unsigned short*)alloc((size_t)kC * kC * 2);
  unsigned short* Wlo_c = (unsigned short*)alloc((size_t)kC * kC * 2);
  float* a_src_rc = (float*)alloc((size_t)kN * kH * 4);
  float* a_dst_rc = (float*)alloc((size_t)kN * kH * 4);
  float* a_src_cr = (float*)alloc((size_t)kN * kH * 4);
  float* a_dst_cr = (float*)alloc((size_t)kN * kH * 4);
  int* cnt_rc  = (int*)alloc((size_t)kN * 4);
  int* off_rc  = (int*)alloc((size_t)kN * 4);
  int* cur_rc  = (int*)alloc((size_t)kN * 4);
  int* perm_rc = (int*)alloc((size_t)kE * 4);
  int* cnt_cr  = (int*)alloc((size_t)kN * 4);
  int* off_cr  = (int*)alloc((size_t)kN * 4);
  int* cur_cr  = (int*)alloc((size_t)kN * 4);
  int* perm_cr = (int*)alloc((size_t)kE * 4);
  int*   part  = (int*)alloc(512 * 4);
  float* stats = (float*)alloc(1024 * 4);
  float* sb    = (float*)alloc(1024 * 4);

  const int nScanB = (kN + 255) / 256;  // 391
  const int nX4    = kN * kC / 4;       // 6.4M float4
  const int nW4    = kC * kC / 4;       // 16384 float4

  zero_kernel<<<nScanB, 256, 0, stream>>>(cnt_rc, kN);
  zero_kernel<<<nScanB, 256, 0, stream>>>(cnt_cr, kN);
  zero_kernel<<<4, 256, 0, stream>>>((int*)stats, 1024);

  // weight conversion (tiny)
  cvt_kernel<<<(nW4 + 255) / 256, 256, 0, stream>>>(W_req, Whi_r, Wlo_r, nW4);
  cvt_kernel<<<(nW4 + 255) / 256, 256, 0, stream>>>(W_code, Whi_c, Wlo_c, nW4);

  // projections, per node type (X region reused)
  dim3 ggrid(kC / 128, kNpad / 128);
  cvt_kernel<<<(nX4 + 255) / 256, 256, 0, stream>>>(x_req, Xhi, Xlo, nX4);
  gemm_kernel<<<ggrid, 256, 0, stream>>>(Xhi, Xlo, Whi_r, Wlo_r, b_req, h_req, kN);
  cvt_kernel<<<(nX4 + 255) / 256, 256, 0, stream>>>(x_code, Xhi, Xlo, nX4);
  gemm_kernel<<<ggrid, 256, 0, stream>>>(Xhi, Xlo, Whi_c, Wlo_c, b_code, h_code, kN);

  // attention scalars: req is src in rc / dst in cr; code is src in cr / dst in rc
  avec_kernel<<<(kN + 3) / 4, 256, 0, stream>>>(h_req, att_src_rc, att_dst_cr,
                                                a_src_rc, a_dst_cr, kN);
  avec_kernel<<<(kN + 3) / 4, 256, 0, stream>>>(h_code, att_src_cr, att_dst_rc,
                                                a_src_cr, a_dst_rc, kN);

  // CSR build (dst-sorted edge permutation per direction)
  const int* dst_rc = ei_rc + kE;
  const int* dst_cr = ei_cr + kE;
  count_kernel<<<(kE + 255) / 256, 256, 0, stream>>>(dst_rc, kE, cnt_rc);
  count_kernel<<<(kE + 255) / 256, 256, 0, stream>>>(dst_cr, kE, cnt_cr);
  scan1_kernel<<<nScanB, 256, 0, stream>>>(cnt_rc, kN, off_rc, part);
  scan2_kernel<<<1, 512, 0, stream>>>(part, nScanB);
  scan3_kernel<<<nScanB, 256, 0, stream>>>(off_rc, cur_rc, part, kN);
  scan1_kernel<<<nScanB, 256, 0, stream>>>(cnt_cr, kN, off_cr, part);
  scan2_kernel<<<1, 512, 0, stream>>>(part, nScanB);
  scan3_kernel<<<nScanB, 256, 0, stream>>>(off_cr, cur_cr, part, kN);
  scatter_kernel<<<(kE + 255) / 256, 256, 0, stream>>>(dst_rc, kE, cur_rc, perm_rc);
  scatter_kernel<<<(kE + 255) / 256, 256, 0, stream>>>(dst_cr, kE, cur_cr, perm_cr);

  // fused attention softmax + aggregation + relu
  // rc first (reads h_req, writes out_code over the dead X region)...
  aggregate_kernel<<<(kN + 3) / 4, 256, 0, stream>>>(
      h_req, a_src_rc, a_dst_rc, ei_rc, off_rc, cnt_rc, perm_rc, out_code, kN);
  // ...then cr (reads h_code, writes out_req)
  aggregate_kernel<<<(kN + 3) / 4, 256, 0, stream>>>(
      h_code, a_src_cr, a_dst_cr, ei_cr, off_cr, cnt_cr, perm_cr, out_req, kN);

  // BatchNorm (training-mode batch stats) folded into per-channel scale/bias
  bn_stats_kernel<<<256, 256, 0, stream>>>(out_req, kN, stats, stats + 256);
  bn_stats_kernel<<<256, 256, 0, stream>>>(out_code, kN, stats + 512, stats + 768);
  bn_final_kernel<<<1, 256, 0, stream>>>(stats, gamma, beta, sb);

  // edge dot-product classifier
  classify_kernel<<<(kEL + 3) / 4, 256, 0, stream>>>(
      out_req, out_code, el, el + kEL, sb, y, kEL);
}

// Round 4
// 1063.162 us; speedup vs baseline: 1.2154x; 1.0676x over previous
//
#include <hip/hip_runtime.h>
#include <cstdint>
#include <cstddef>

namespace {

constexpr int kN    = 100000;  // nodes per type (N_REQ == N_CODE)
constexpr int kNpad = 100096;  // 782*128, GEMM tile-padded row count
constexpr int kE    = 500000;  // edges per direction
constexpr int kEL   = 200000;  // label edges
constexpr int kC    = 256;     // channels
constexpr int kH    = 8;       // heads
constexpr float kNegSlope = 0.2f;
constexpr float kBnEps    = 1e-5f;

typedef float    f32x4  __attribute__((ext_vector_type(4)));
typedef __bf16   bf16x8 __attribute__((ext_vector_type(8)));
typedef _Float16 h4     __attribute__((ext_vector_type(4)));

__device__ inline unsigned short bf16_rtn(float x) {
  unsigned u = __builtin_bit_cast(unsigned, x);
  unsigned r = (u + 0x7fffu + ((u >> 16) & 1u)) >> 16;
  return (unsigned short)r;
}
__device__ inline float bf16_f(unsigned short h) {
  unsigned u = ((unsigned)h) << 16;
  return __builtin_bit_cast(float, u);
}

// async global->LDS, 16 B per lane; lds base must be wave-uniform (lane*16 added by HW)
__device__ inline void async_copy16(unsigned short* lds, const unsigned short* g) {
  __builtin_amdgcn_global_load_lds(
      (const __attribute__((address_space(1))) unsigned int*)g,
      (__attribute__((address_space(3))) unsigned int*)lds, 16, 0, 0);
}

// ------------- zero-fill (graph-capture-safe) -------------
__global__ void zero_kernel(int* __restrict__ p, int n) {
  const int i = blockIdx.x * 256 + threadIdx.x;
  if (i < n) p[i] = 0;
}

// ------------- fp32 -> split bf16 (hi/lo) conversion, streaming -------------
__global__ __launch_bounds__(256) void cvt_kernel(
    const float* __restrict__ in, unsigned short* __restrict__ hi,
    unsigned short* __restrict__ lo, int n4) {
  const int i = blockIdx.x * 256 + threadIdx.x;
  if (i >= n4) return;
  const float4 v = ((const float4*)in)[i];
  const unsigned short h0 = bf16_rtn(v.x), h1 = bf16_rtn(v.y),
                       h2 = bf16_rtn(v.z), h3 = bf16_rtn(v.w);
  ((ushort4*)hi)[i] = make_ushort4(h0, h1, h2, h3);
  ((ushort4*)lo)[i] = make_ushort4(bf16_rtn(v.x - bf16_f(h0)),
                                   bf16_rtn(v.y - bf16_f(h1)),
                                   bf16_rtn(v.z - bf16_f(h2)),
                                   bf16_rtn(v.w - bf16_f(h3)));
}

// ------------- GEMM (m97 structure): H[M,256] = X @ W^T + b, fp16 out -------------
// split-bf16: H ~= Xhi*Whi + Xhi*Wlo + Xlo*Whi  (3 MFMA passes)
// LDS tiles 128x32 bf16 row-major, staged via global_load_lds dwordx4 (1 tile/wave).
__global__ __launch_bounds__(256) void gemm_kernel(
    const unsigned short* __restrict__ Ahi, const unsigned short* __restrict__ Alo,
    const unsigned short* __restrict__ Bhi, const unsigned short* __restrict__ Blo,
    const float* __restrict__ bias, _Float16* __restrict__ H, int M) {
  __shared__ unsigned short sAhi[128 * 32];
  __shared__ unsigned short sAlo[128 * 32];
  __shared__ unsigned short sBhi[128 * 32];
  __shared__ unsigned short sBlo[128 * 32];

  const int tid  = threadIdx.x;
  const int m0   = blockIdx.y * 128;
  const int n0   = blockIdx.x * 128;
  const int w    = tid >> 6, lane = tid & 63, l16 = lane & 15, quad = lane >> 4;
  const int wm   = (w >> 1) * 64, wn = (w & 1) * 64;

  // wave w stages tile w: 0=Ahi 1=Alo 2=Bhi 3=Blo
  const unsigned short* gsrc = (w == 0) ? Ahi : (w == 1) ? Alo : (w == 2) ? Bhi : Blo;
  unsigned short* lds        = (w == 0) ? sAhi : (w == 1) ? sAlo : (w == 2) ? sBhi : sBlo;
  const int row0 = (w < 2) ? m0 : n0;
  // lane L covers (row = 16j + L/4, 16B chunk L%4) of chunk j
  const size_t gbase = (size_t)(row0 + (lane >> 2)) * kC + (lane & 3) * 8;

  f32x4 acc[4][4] = {};

  for (int kt = 0; kt < kC / 32; ++kt) {
    const int k0 = kt * 32;
    __syncthreads();  // prior ds_reads done before overwrite
#pragma unroll
    for (int j = 0; j < 8; ++j)
      async_copy16(lds + j * 512, gsrc + gbase + (size_t)j * 16 * kC + k0);
    __syncthreads();  // drains vmcnt (global_load_lds) before ds_read

    bf16x8 ah[4], al[4], bh[4], bl[4];
#pragma unroll
    for (int mi = 0; mi < 4; ++mi) {
      const int row = wm + mi * 16 + l16;
      ah[mi] = *(const bf16x8*)&sAhi[row * 32 + quad * 8];
      al[mi] = *(const bf16x8*)&sAlo[row * 32 + quad * 8];
    }
#pragma unroll
    for (int ni = 0; ni < 4; ++ni) {
      const int row = wn + ni * 16 + l16;
      bh[ni] = *(const bf16x8*)&sBhi[row * 32 + quad * 8];
      bl[ni] = *(const bf16x8*)&sBlo[row * 32 + quad * 8];
    }
#pragma unroll
    for (int mi = 0; mi < 4; ++mi)
#pragma unroll
      for (int ni = 0; ni < 4; ++ni) {
        acc[mi][ni] = __builtin_amdgcn_mfma_f32_16x16x32_bf16(ah[mi], bh[ni], acc[mi][ni], 0, 0, 0);
        acc[mi][ni] = __builtin_amdgcn_mfma_f32_16x16x32_bf16(ah[mi], bl[ni], acc[mi][ni], 0, 0, 0);
        acc[mi][ni] = __builtin_amdgcn_mfma_f32_16x16x32_bf16(al[mi], bh[ni], acc[mi][ni], 0, 0, 0);
      }
  }

  // epilogue: D[row=quad*4+r][col=l16] per 16x16 tile; +bias, fp16 store
#pragma unroll
  for (int ni = 0; ni < 4; ++ni) {
    const int col = n0 + wn + ni * 16 + l16;
    const float bc = bias[col];
#pragma unroll
    for (int mi = 0; mi < 4; ++mi) {
      const int gm0 = m0 + wm + mi * 16 + quad * 4;
#pragma unroll
      for (int r = 0; r < 4; ++r) {
        const int gm = gm0 + r;
        if (gm < M) H[(size_t)gm * kC + col] = (_Float16)(acc[mi][ni][r] + bc);
      }
    }
  }
}

// ------------- per-node attention scalars: a[n,h] = <h[n,h,:], att[h,:]> -------------
__global__ __launch_bounds__(256) void avec_kernel(
    const _Float16* __restrict__ h, const float* __restrict__ attA,
    const float* __restrict__ attB, float* __restrict__ outA,
    float* __restrict__ outB, int N) {
  const int n = blockIdx.x * 4 + (threadIdx.x >> 6);
  if (n >= N) return;
  const int L = threadIdx.x & 63;
  const h4 hv = *(const h4*)&h[(size_t)n * kC + 4 * L];
  const float4 a = *(const float4*)&attA[4 * L];
  const float4 b = *(const float4*)&attB[4 * L];
  const float hx = (float)hv.x, hy = (float)hv.y, hz = (float)hv.z, hw = (float)hv.w;
  float pa = hx * a.x + hy * a.y + hz * a.z + hw * a.w;
  float pb = hx * b.x + hy * b.y + hz * b.z + hw * b.w;
  for (int m = 1; m < 8; m <<= 1) {
    pa += __shfl_xor(pa, m);
    pb += __shfl_xor(pb, m);
  }
  if ((L & 7) == 0) {
    outA[n * kH + (L >> 3)] = pa;
    outB[n * kH + (L >> 3)] = pb;
  }
}

// ------------- CSR build -------------
__global__ void count_kernel(const int* __restrict__ dst, int E, int* __restrict__ cnt) {
  const int e = blockIdx.x * 256 + threadIdx.x;
  if (e < E) atomicAdd(&cnt[dst[e]], 1);
}

__global__ void scan1_kernel(const int* __restrict__ cnt, int N,
                             int* __restrict__ off, int* __restrict__ part) {
  __shared__ int s[256];
  const int t = threadIdx.x;
  const int i = blockIdx.x * 256 + t;
  const int v = (i < N) ? cnt[i] : 0;
  s[t] = v;
  __syncthreads();
  for (int o = 1; o < 256; o <<= 1) {
    const int x = (t >= o) ? s[t - o] : 0;
    __syncthreads();
    s[t] += x;
    __syncthreads();
  }
  if (i < N) off[i] = s[t] - v;
  if (t == 255) part[blockIdx.x] = s[255];
}

__global__ void scan2_kernel(int* __restrict__ part, int NB) {  // one block, 512 thr
  __shared__ int s[512];
  const int t = threadIdx.x;
  const int v = (t < NB) ? part[t] : 0;
  s[t] = v;
  __syncthreads();
  for (int o = 1; o < 512; o <<= 1) {
    const int x = (t >= o) ? s[t - o] : 0;
    __syncthreads();
    s[t] += x;
    __syncthreads();
  }
  if (t < NB) part[t] = s[t] - v;
}

__global__ void scan3_kernel(int* __restrict__ off, int* __restrict__ cur,
                             const int* __restrict__ part, int N) {
  const int i = blockIdx.x * 256 + threadIdx.x;
  if (i < N) {
    const int v = off[i] + part[blockIdx.x];
    off[i] = v;
    cur[i] = v;
  }
}

__global__ void scatter_kernel(const int* __restrict__ dst, int E,
                               int* __restrict__ cur, int* __restrict__ perm) {
  const int e = blockIdx.x * 256 + threadIdx.x;
  if (e < E) {
    const int p = atomicAdd(&cur[dst[e]], 1);
    perm[p] = e;
  }
}

// ------------- fused segment-softmax + weighted aggregate + relu -------------
__global__ __launch_bounds__(256) void aggregate_kernel(
    const _Float16* __restrict__ hsrc, const float* __restrict__ aS,
    const float* __restrict__ aD, const int* __restrict__ src,
    const int* __restrict__ off, const int* __restrict__ cnt,
    const int* __restrict__ perm, float* __restrict__ out, int Ndst) {
  const int d = blockIdx.x * 4 + (threadIdx.x >> 6);
  if (d >= Ndst) return;
  const int L  = threadIdx.x & 63;
  const int hd = L >> 3;  // lane's 4 channels all in head L>>3
  const float ad = aD[d * kH + hd];
  const int o = off[d], c = cnt[d];
  float4 acc = make_float4(0.f, 0.f, 0.f, 0.f);
  float se = 0.f;
  for (int i = 0; i < c; ++i) {
    const int e = perm[o + i];
    const int s = src[e];
    float t = aS[s * kH + hd] + ad;
    t = t > 0.f ? t : kNegSlope * t;
    const float wgt = __expf(t);
    se += wgt;
    const h4 hv = *(const h4*)&hsrc[(size_t)s * kC + 4 * L];
    acc.x += wgt * (float)hv.x;
    acc.y += wgt * (float)hv.y;
    acc.z += wgt * (float)hv.z;
    acc.w += wgt * (float)hv.w;
  }
  const float inv = 1.f / (se + 1e-16f);
  float4 r;
  r.x = fmaxf(acc.x * inv, 0.f);
  r.y = fmaxf(acc.y * inv, 0.f);
  r.z = fmaxf(acc.z * inv, 0.f);
  r.w = fmaxf(acc.w * inv, 0.f);
  *(float4*)&out[(size_t)d * kC + 4 * L] = r;
}

// ------------- BatchNorm stats (biased var), high-parallelism version -------------
// 1024 blocks; wave w of block b covers rows r0+w, r0+w+4, ...; lane L covers
// channels 4L..4L+3 via float4 loads (1 KB/wave/iter). LDS cross-wave reduce,
// then one atomicAdd per channel per block (sum & sumsq).
constexpr int kBnBlocks = 1024;
__global__ __launch_bounds__(256) void bn_stats_kernel(
    const float* __restrict__ x, int N, float* __restrict__ sum,
    float* __restrict__ sumsq) {
  __shared__ f32x4 red[2][4][64];
  const int t = threadIdx.x, w = t >> 6, L = t & 63;
  const int rowsPer = (N + kBnBlocks - 1) / kBnBlocks;  // 98
  const int r0 = blockIdx.x * rowsPer;
  const int r1 = min(r0 + rowsPer, N);
  f32x4 s = {0.f, 0.f, 0.f, 0.f}, s2 = {0.f, 0.f, 0.f, 0.f};
  for (int r = r0 + w; r < r1; r += 4) {
    const f32x4 v = *(const f32x4*)&x[(size_t)r * kC + 4 * L];
    s += v;
    s2 += v * v;
  }
  red[0][w][L] = s;
  red[1][w][L] = s2;
  __syncthreads();
  if (w == 0) {
    f32x4 ts = red[0][0][L] + red[0][1][L] + red[0][2][L] + red[0][3][L];
    f32x4 t2 = red[1][0][L] + red[1][1][L] + red[1][2][L] + red[1][3][L];
    atomicAdd(&sum[4 * L + 0], ts[0]);
    atomicAdd(&sum[4 * L + 1], ts[1]);
    atomicAdd(&sum[4 * L + 2], ts[2]);
    atomicAdd(&sum[4 * L + 3], ts[3]);
    atomicAdd(&sumsq[4 * L + 0], t2[0]);
    atomicAdd(&sumsq[4 * L + 1], t2[1]);
    atomicAdd(&sumsq[4 * L + 2], t2[2]);
    atomicAdd(&sumsq[4 * L + 3], t2[3]);
  }
}

__global__ void bn_final_kernel(const float* __restrict__ stats,
                                const float* __restrict__ gamma,
                                const float* __restrict__ beta,
                                float* __restrict__ sb) {
  const int c = threadIdx.x;
  for (int t = 0; t < 2; ++t) {
    const float mu  = stats[t * 512 + c] * (1.f / kN);
    const float var = stats[t * 512 + 256 + c] * (1.f / kN) - mu * mu;
    const float sc  = gamma[c] * rsqrtf(var + kBnEps);
    sb[t * 512 + c]       = sc;
    sb[t * 512 + 256 + c] = beta[c] - mu * sc;
  }
}

// ------------- edge classifier: sigmoid(<z_req[i], z_code[j]>), BN fused -------------
__global__ __launch_bounds__(256) void classify_kernel(
    const float* __restrict__ zr, const float* __restrict__ zc,
    const int* __restrict__ ei, const int* __restrict__ ej,
    const float* __restrict__ sb, float* __restrict__ y, int EL) {
  const int e = blockIdx.x * 4 + (threadIdx.x >> 6);
  if (e >= EL) return;
  const int L = threadIdx.x & 63;
  const int i = ei[e], j = ej[e];
  const float4 a  = *(const float4*)&zr[(size_t)i * kC + 4 * L];
  const float4 b  = *(const float4*)&zc[(size_t)j * kC + 4 * L];
  const float4 sr = *(const float4*)&sb[4 * L];
  const float4 br = *(const float4*)&sb[256 + 4 * L];
  const float4 sc = *(const float4*)&sb[512 + 4 * L];
  const float4 bc = *(const float4*)&sb[768 + 4 * L];
  float p = (a.x * sr.x + br.x) * (b.x * sc.x + bc.x) +
            (a.y * sr.y + br.y) * (b.y * sc.y + bc.y) +
            (a.z * sr.z + br.z) * (b.z * sc.z + bc.z) +
            (a.w * sr.w + br.w) * (b.w * sc.w + bc.w);
  for (int m = 1; m < 64; m <<= 1) p += __shfl_xor(p, m);
  if (L == 0) y[e] = 1.f / (1.f + __expf(-p));
}

}  // namespace

extern "C" void kernel_launch(void* const* d_in, const int* in_sizes, int n_in,
                              void* d_out, int out_size, void* d_ws, size_t ws_size,
                              hipStream_t stream) {
  (void)in_sizes; (void)n_in; (void)out_size; (void)ws_size;
  const float* x_req      = (const float*)d_in[0];
  const float* x_code     = (const float*)d_in[1];
  const int*   ei_rc      = (const int*)d_in[2];   // [src(E) | dst(E)] req -> code
  const int*   ei_cr      = (const int*)d_in[3];   // [src(E) | dst(E)] code -> req
  const int*   el         = (const int*)d_in[4];   // [req(EL) | code(EL)]
  const float* W_req      = (const float*)d_in[5];
  const float* b_req      = (const float*)d_in[6];
  const float* W_code     = (const float*)d_in[7];
  const float* b_code     = (const float*)d_in[8];
  const float* att_src_rc = (const float*)d_in[9];
  const float* att_dst_rc = (const float*)d_in[10];
  const float* att_src_cr = (const float*)d_in[11];
  const float* att_dst_cr = (const float*)d_in[12];
  // d_in[13..15] = k_W, k_b, q : semantic attn over ONE metapath == identity -> unused
  const float* gamma      = (const float*)d_in[16];
  const float* beta       = (const float*)d_in[17];
  float* y = (float*)d_out;

  // ---- workspace (~325 MB peak) ----
  char* p = (char*)d_ws;
  auto alloc = [&](size_t bytes) {
    char* r = p;
    p += (bytes + 1023) & ~(size_t)1023;
    return r;
  };
  // X split-bf16 region, reused per node type; reused again as out_code after GEMMs
  unsigned short* Xhi = (unsigned short*)alloc((size_t)kNpad * kC * 2);  // 51.25 MB
  unsigned short* Xlo = (unsigned short*)alloc((size_t)kNpad * kC * 2);  // 51.25 MB
  float* out_code = (float*)Xhi;  // alias: X dead after both GEMMs (needs 102.4 MB)
  _Float16* h_req  = (_Float16*)alloc((size_t)kN * kC * 2);  // 51.2 MB
  _Float16* h_code = (_Float16*)alloc((size_t)kN * kC * 2);  // 51.2 MB
  float* out_req   = (float*)alloc((size_t)kN * kC * 4);     // 102.4 MB
  unsigned short* Whi_r = (unsigned short*)alloc((size_t)kC * kC * 2);
  unsigned short* Wlo_r = (unsigned short*)alloc((size_t)kC * kC * 2);
  unsigned short* Whi_c = (unsigned short*)alloc((size_t)kC * kC * 2);
  unsigned short* Wlo_c = (unsigned short*)alloc((size_t)kC * kC * 2);
  float* a_src_rc = (float*)alloc((size_t)kN * kH * 4);
  float* a_dst_rc = (float*)alloc((size_t)kN * kH * 4);
  float* a_src_cr = (float*)alloc((size_t)kN * kH * 4);
  float* a_dst_cr = (float*)alloc((size_t)kN * kH * 4);
  int* cnt_rc  = (int*)alloc((size_t)kN * 4);
  int* off_rc  = (int*)alloc((size_t)kN * 4);
  int* cur_rc  = (int*)alloc((size_t)kN * 4);
  int* perm_rc = (int*)alloc((size_t)kE * 4);
  int* cnt_cr  = (int*)alloc((size_t)kN * 4);
  int* off_cr  = (int*)alloc((size_t)kN * 4);
  int* cur_cr  = (int*)alloc((size_t)kN * 4);
  int* perm_cr = (int*)alloc((size_t)kE * 4);
  int*   part  = (int*)alloc(512 * 4);
  float* stats = (float*)alloc(1024 * 4);
  float* sb    = (float*)alloc(1024 * 4);

  const int nScanB = (kN + 255) / 256;  // 391
  const int nX4    = kN * kC / 4;       // 6.4M float4
  const int nW4    = kC * kC / 4;       // 16384 float4

  zero_kernel<<<nScanB, 256, 0, stream>>>(cnt_rc, kN);
  zero_kernel<<<nScanB, 256, 0, stream>>>(cnt_cr, kN);
  zero_kernel<<<4, 256, 0, stream>>>((int*)stats, 1024);

  // weight conversion (tiny)
  cvt_kernel<<<(nW4 + 255) / 256, 256, 0, stream>>>(W_req, Whi_r, Wlo_r, nW4);
  cvt_kernel<<<(nW4 + 255) / 256, 256, 0, stream>>>(W_code, Whi_c, Wlo_c, nW4);

  // projections, per node type (X region reused)
  dim3 ggrid(kC / 128, kNpad / 128);
  cvt_kernel<<<(nX4 + 255) / 256, 256, 0, stream>>>(x_req, Xhi, Xlo, nX4);
  gemm_kernel<<<ggrid, 256, 0, stream>>>(Xhi, Xlo, Whi_r, Wlo_r, b_req, h_req, kN);
  cvt_kernel<<<(nX4 + 255) / 256, 256, 0, stream>>>(x_code, Xhi, Xlo, nX4);
  gemm_kernel<<<ggrid, 256, 0, stream>>>(Xhi, Xlo, Whi_c, Wlo_c, b_code, h_code, kN);

  // attention scalars: req is src in rc / dst in cr; code is src in cr / dst in rc
  avec_kernel<<<(kN + 3) / 4, 256, 0, stream>>>(h_req, att_src_rc, att_dst_cr,
                                                a_src_rc, a_dst_cr, kN);
  avec_kernel<<<(kN + 3) / 4, 256, 0, stream>>>(h_code, att_src_cr, att_dst_rc,
                                                a_src_cr, a_dst_rc, kN);

  // CSR build (dst-sorted edge permutation per direction)
  const int* dst_rc = ei_rc + kE;
  const int* dst_cr = ei_cr + kE;
  count_kernel<<<(kE + 255) / 256, 256, 0, stream>>>(dst_rc, kE, cnt_rc);
  count_kernel<<<(kE + 255) / 256, 256, 0, stream>>>(dst_cr, kE, cnt_cr);
  scan1_kernel<<<nScanB, 256, 0, stream>>>(cnt_rc, kN, off_rc, part);
  scan2_kernel<<<1, 512, 0, stream>>>(part, nScanB);
  scan3_kernel<<<nScanB, 256, 0, stream>>>(off_rc, cur_rc, part, kN);
  scan1_kernel<<<nScanB, 256, 0, stream>>>(cnt_cr, kN, off_cr, part);
  scan2_kernel<<<1, 512, 0, stream>>>(part, nScanB);
  scan3_kernel<<<nScanB, 256, 0, stream>>>(off_cr, cur_cr, part, kN);
  scatter_kernel<<<(kE + 255) / 256, 256, 0, stream>>>(dst_rc, kE, cur_rc, perm_rc);
  scatter_kernel<<<(kE + 255) / 256, 256, 0, stream>>>(dst_cr, kE, cur_cr, perm_cr);

  // fused attention softmax + aggregation + relu
  // rc first (reads h_req, writes out_code over the dead X region)...
  aggregate_kernel<<<(kN + 3) / 4, 256, 0, stream>>>(
      h_req, a_src_rc, a_dst_rc, ei_rc, off_rc, cnt_rc, perm_rc, out_code, kN);
  // ...then cr (reads h_code, writes out_req)
  aggregate_kernel<<<(kN + 3) / 4, 256, 0, stream>>>(
      h_code, a_src_cr, a_dst_cr, ei_cr, off_cr, cnt_cr, perm_cr, out_req, kN);

  // BatchNorm (training-mode batch stats) folded into per-channel scale/bias
  bn_stats_kernel<<<kBnBlocks, 256, 0, stream>>>(out_req, kN, stats, stats + 256);
  bn_stats_kernel<<<kBnBlocks, 256, 0, stream>>>(out_code, kN, stats + 512, stats + 768);
  bn_final_kernel<<<1, 256, 0, stream>>>(stats, gamma, beta, sb);

  // edge dot-product classifier
  classify_kernel<<<(kEL + 3) / 4, 256, 0, stream>>>(
      out_req, out_code, el, el + kEL, sb, y, kEL);
}

// Round 5
// 1062.603 us; speedup vs baseline: 1.2160x; 1.0005x over previous
//
#include <hip/hip_runtime.h>
#include <cstdint>
#include <cstddef>

namespace {

constexpr int kN    = 100000;  // nodes per type (N_REQ == N_CODE)
constexpr int kNpad = 100096;  // 782*128, GEMM tile-padded row count
constexpr int kE    = 500000;  // edges per direction
constexpr int kEL   = 200000;  // label edges
constexpr int kC    = 256;     // channels
constexpr int kH    = 8;       // heads
constexpr float kNegSlope = 0.2f;
constexpr float kBnEps    = 1e-5f;

typedef float    f32x4  __attribute__((ext_vector_type(4)));
typedef __bf16   bf16x8 __attribute__((ext_vector_type(8)));
typedef _Float16 h4     __attribute__((ext_vector_type(4)));

__device__ inline unsigned short bf16_rtn(float x) {
  unsigned u = __builtin_bit_cast(unsigned, x);
  unsigned r = (u + 0x7fffu + ((u >> 16) & 1u)) >> 16;
  return (unsigned short)r;
}
__device__ inline float bf16_f(unsigned short h) {
  unsigned u = ((unsigned)h) << 16;
  return __builtin_bit_cast(float, u);
}

// async global->LDS, 16 B per lane; lds base must be wave-uniform (lane*16 added by HW)
__device__ inline void async_copy16(unsigned short* lds, const unsigned short* g) {
  __builtin_amdgcn_global_load_lds(
      (const __attribute__((address_space(1))) unsigned int*)g,
      (__attribute__((address_space(3))) unsigned int*)lds, 16, 0, 0);
}

// ------------- zero-fill (graph-capture-safe) -------------
__global__ void zero_kernel(int* __restrict__ p, int n) {
  const int i = blockIdx.x * 256 + threadIdx.x;
  if (i < n) p[i] = 0;
}

// ------------- fp32 -> split bf16 (hi/lo) conversion, streaming -------------
__global__ __launch_bounds__(256) void cvt_kernel(
    const float* __restrict__ in, unsigned short* __restrict__ hi,
    unsigned short* __restrict__ lo, int n4) {
  const int i = blockIdx.x * 256 + threadIdx.x;
  if (i >= n4) return;
  const float4 v = ((const float4*)in)[i];
  const unsigned short h0 = bf16_rtn(v.x), h1 = bf16_rtn(v.y),
                       h2 = bf16_rtn(v.z), h3 = bf16_rtn(v.w);
  ((ushort4*)hi)[i] = make_ushort4(h0, h1, h2, h3);
  ((ushort4*)lo)[i] = make_ushort4(bf16_rtn(v.x - bf16_f(h0)),
                                   bf16_rtn(v.y - bf16_f(h1)),
                                   bf16_rtn(v.z - bf16_f(h2)),
                                   bf16_rtn(v.w - bf16_f(h3)));
}

// ------------- GEMM (m97 structure): H[M,256] = X @ W^T + b, fp16 out -------------
// split-bf16: H ~= Xhi*Whi + Xhi*Wlo + Xlo*Whi  (3 MFMA passes)
// LDS tiles 128x32 bf16 row-major, staged via global_load_lds dwordx4 (1 tile/wave).
__global__ __launch_bounds__(256) void gemm_kernel(
    const unsigned short* __restrict__ Ahi, const unsigned short* __restrict__ Alo,
    const unsigned short* __restrict__ Bhi, const unsigned short* __restrict__ Blo,
    const float* __restrict__ bias, _Float16* __restrict__ H, int M) {
  __shared__ unsigned short sAhi[128 * 32];
  __shared__ unsigned short sAlo[128 * 32];
  __shared__ unsigned short sBhi[128 * 32];
  __shared__ unsigned short sBlo[128 * 32];

  const int tid  = threadIdx.x;
  const int m0   = blockIdx.y * 128;
  const int n0   = blockIdx.x * 128;
  const int w    = tid >> 6, lane = tid & 63, l16 = lane & 15, quad = lane >> 4;
  const int wm   = (w >> 1) * 64, wn = (w & 1) * 64;

  // wave w stages tile w: 0=Ahi 1=Alo 2=Bhi 3=Blo
  const unsigned short* gsrc = (w == 0) ? Ahi : (w == 1) ? Alo : (w == 2) ? Bhi : Blo;
  unsigned short* lds        = (w == 0) ? sAhi : (w == 1) ? sAlo : (w == 2) ? sBhi : sBlo;
  const int row0 = (w < 2) ? m0 : n0;
  // lane L covers (row = 16j + L/4, 16B chunk L%4) of chunk j
  const size_t gbase = (size_t)(row0 + (lane >> 2)) * kC + (lane & 3) * 8;

  f32x4 acc[4][4] = {};

  for (int kt = 0; kt < kC / 32; ++kt) {
    const int k0 = kt * 32;
    __syncthreads();  // prior ds_reads done before overwrite
#pragma unroll
    for (int j = 0; j < 8; ++j)
      async_copy16(lds + j * 512, gsrc + gbase + (size_t)j * 16 * kC + k0);
    __syncthreads();  // drains vmcnt (global_load_lds) before ds_read

    bf16x8 ah[4], al[4], bh[4], bl[4];
#pragma unroll
    for (int mi = 0; mi < 4; ++mi) {
      const int row = wm + mi * 16 + l16;
      ah[mi] = *(const bf16x8*)&sAhi[row * 32 + quad * 8];
      al[mi] = *(const bf16x8*)&sAlo[row * 32 + quad * 8];
    }
#pragma unroll
    for (int ni = 0; ni < 4; ++ni) {
      const int row = wn + ni * 16 + l16;
      bh[ni] = *(const bf16x8*)&sBhi[row * 32 + quad * 8];
      bl[ni] = *(const bf16x8*)&sBlo[row * 32 + quad * 8];
    }
#pragma unroll
    for (int mi = 0; mi < 4; ++mi)
#pragma unroll
      for (int ni = 0; ni < 4; ++ni) {
        acc[mi][ni] = __builtin_amdgcn_mfma_f32_16x16x32_bf16(ah[mi], bh[ni], acc[mi][ni], 0, 0, 0);
        acc[mi][ni] = __builtin_amdgcn_mfma_f32_16x16x32_bf16(ah[mi], bl[ni], acc[mi][ni], 0, 0, 0);
        acc[mi][ni] = __builtin_amdgcn_mfma_f32_16x16x32_bf16(al[mi], bh[ni], acc[mi][ni], 0, 0, 0);
      }
  }

  // epilogue: D[row=quad*4+r][col=l16] per 16x16 tile; +bias, fp16 store
#pragma unroll
  for (int ni = 0; ni < 4; ++ni) {
    const int col = n0 + wn + ni * 16 + l16;
    const float bc = bias[col];
#pragma unroll
    for (int mi = 0; mi < 4; ++mi) {
      const int gm0 = m0 + wm + mi * 16 + quad * 4;
#pragma unroll
      for (int r = 0; r < 4; ++r) {
        const int gm = gm0 + r;
        if (gm < M) H[(size_t)gm * kC + col] = (_Float16)(acc[mi][ni][r] + bc);
      }
    }
  }
}

// ------------- per-node attention scalars: a[n,h] = <h[n,h,:], att[h,:]> -------------
__global__ __launch_bounds__(256) void avec_kernel(
    const _Float16* __restrict__ h, const float* __restrict__ attA,
    const float* __restrict__ attB, float* __restrict__ outA,
    float* __restrict__ outB, int N) {
  const int n = blockIdx.x * 4 + (threadIdx.x >> 6);
  if (n >= N) return;
  const int L = threadIdx.x & 63;
  const h4 hv = *(const h4*)&h[(size_t)n * kC + 4 * L];
  const float4 a = *(const float4*)&attA[4 * L];
  const float4 b = *(const float4*)&attB[4 * L];
  const float hx = (float)hv.x, hy = (float)hv.y, hz = (float)hv.z, hw = (float)hv.w;
  float pa = hx * a.x + hy * a.y + hz * a.z + hw * a.w;
  float pb = hx * b.x + hy * b.y + hz * b.z + hw * b.w;
  for (int m = 1; m < 8; m <<= 1) {
    pa += __shfl_xor(pa, m);
    pb += __shfl_xor(pb, m);
  }
  if ((L & 7) == 0) {
    outA[n * kH + (L >> 3)] = pa;
    outB[n * kH + (L >> 3)] = pb;
  }
}

// ------------- CSR build -------------
__global__ void count_kernel(const int* __restrict__ dst, int E, int* __restrict__ cnt) {
  const int e = blockIdx.x * 256 + threadIdx.x;
  if (e < E) atomicAdd(&cnt[dst[e]], 1);
}

__global__ void scan1_kernel(const int* __restrict__ cnt, int N,
                             int* __restrict__ off, int* __restrict__ part) {
  __shared__ int s[256];
  const int t = threadIdx.x;
  const int i = blockIdx.x * 256 + t;
  const int v = (i < N) ? cnt[i] : 0;
  s[t] = v;
  __syncthreads();
  for (int o = 1; o < 256; o <<= 1) {
    const int x = (t >= o) ? s[t - o] : 0;
    __syncthreads();
    s[t] += x;
    __syncthreads();
  }
  if (i < N) off[i] = s[t] - v;
  if (t == 255) part[blockIdx.x] = s[255];
}

__global__ void scan2_kernel(int* __restrict__ part, int NB) {  // one block, 512 thr
  __shared__ int s[512];
  const int t = threadIdx.x;
  const int v = (t < NB) ? part[t] : 0;
  s[t] = v;
  __syncthreads();
  for (int o = 1; o < 512; o <<= 1) {
    const int x = (t >= o) ? s[t - o] : 0;
    __syncthreads();
    s[t] += x;
    __syncthreads();
  }
  if (t < NB) part[t] = s[t] - v;
}

__global__ void scan3_kernel(int* __restrict__ off, int* __restrict__ cur,
                             const int* __restrict__ part, int N) {
  const int i = blockIdx.x * 256 + threadIdx.x;
  if (i < N) {
    const int v = off[i] + part[blockIdx.x];
    off[i] = v;
    cur[i] = v;
  }
}

__global__ void scatter_kernel(const int* __restrict__ dst, int E,
                               int* __restrict__ cur, int* __restrict__ perm) {
  const int e = blockIdx.x * 256 + threadIdx.x;
  if (e < E) {
    const int p = atomicAdd(&cur[dst[e]], 1);
    perm[p] = e;
  }
}

// ------------- fused segment-softmax + weighted aggregate + relu -------------
__global__ __launch_bounds__(256) void aggregate_kernel(
    const _Float16* __restrict__ hsrc, const float* __restrict__ aS,
    const float* __restrict__ aD, const int* __restrict__ src,
    const int* __restrict__ off, const int* __restrict__ cnt,
    const int* __restrict__ perm, float* __restrict__ out, int Ndst) {
  const int d = blockIdx.x * 4 + (threadIdx.x >> 6);
  if (d >= Ndst) return;
  const int L  = threadIdx.x & 63;
  const int hd = L >> 3;  // lane's 4 channels all in head L>>3
  const float ad = aD[d * kH + hd];
  const int o = off[d], c = cnt[d];
  float4 acc = make_float4(0.f, 0.f, 0.f, 0.f);
  float se = 0.f;
  for (int i = 0; i < c; ++i) {
    const int e = perm[o + i];
    const int s = src[e];
    float t = aS[s * kH + hd] + ad;
    t = t > 0.f ? t : kNegSlope * t;
    const float wgt = __expf(t);
    se += wgt;
    const h4 hv = *(const h4*)&hsrc[(size_t)s * kC + 4 * L];
    acc.x += wgt * (float)hv.x;
    acc.y += wgt * (float)hv.y;
    acc.z += wgt * (float)hv.z;
    acc.w += wgt * (float)hv.w;
  }
  const float inv = 1.f / (se + 1e-16f);
  float4 r;
  r.x = fmaxf(acc.x * inv, 0.f);
  r.y = fmaxf(acc.y * inv, 0.f);
  r.z = fmaxf(acc.z * inv, 0.f);
  r.w = fmaxf(acc.w * inv, 0.f);
  *(float4*)&out[(size_t)d * kC + 4 * L] = r;
}

// ------------- BatchNorm stats (biased var), MLP-pipelined -------------
// 1024 blocks x 4 waves; wave w covers rows r0+w, r0+w+4, ... with a 4-deep
// unroll (4 independent float4 loads in flight per wave -> 16/SIMD).
constexpr int kBnBlocks = 1024;
__global__ __launch_bounds__(256) void bn_stats_kernel(
    const float* __restrict__ x, int N, float* __restrict__ sum,
    float* __restrict__ sumsq) {
  __shared__ f32x4 red[2][4][64];
  const int t = threadIdx.x, w = t >> 6, L = t & 63;
  const int rowsPer = (N + kBnBlocks - 1) / kBnBlocks;  // 98
  const int r0 = blockIdx.x * rowsPer;
  const int r1 = min(r0 + rowsPer, N);
  f32x4 s0 = {0.f, 0.f, 0.f, 0.f}, q0 = {0.f, 0.f, 0.f, 0.f};
  f32x4 s1 = {0.f, 0.f, 0.f, 0.f}, q1 = {0.f, 0.f, 0.f, 0.f};
  f32x4 s2 = {0.f, 0.f, 0.f, 0.f}, q2 = {0.f, 0.f, 0.f, 0.f};
  f32x4 s3 = {0.f, 0.f, 0.f, 0.f}, q3 = {0.f, 0.f, 0.f, 0.f};
  int r = r0 + w;
  for (; r + 12 < r1; r += 16) {  // 4 independent loads issued back-to-back
    const f32x4 v0 = *(const f32x4*)&x[(size_t)(r)      * kC + 4 * L];
    const f32x4 v1 = *(const f32x4*)&x[(size_t)(r + 4)  * kC + 4 * L];
    const f32x4 v2 = *(const f32x4*)&x[(size_t)(r + 8)  * kC + 4 * L];
    const f32x4 v3 = *(const f32x4*)&x[(size_t)(r + 12) * kC + 4 * L];
    s0 += v0; q0 += v0 * v0;
    s1 += v1; q1 += v1 * v1;
    s2 += v2; q2 += v2 * v2;
    s3 += v3; q3 += v3 * v3;
  }
  for (; r < r1; r += 4) {
    const f32x4 v = *(const f32x4*)&x[(size_t)r * kC + 4 * L];
    s0 += v; q0 += v * v;
  }
  const f32x4 s = (s0 + s1) + (s2 + s3);
  const f32x4 q = (q0 + q1) + (q2 + q3);
  red[0][w][L] = s;
  red[1][w][L] = q;
  __syncthreads();
  if (w == 0) {
    f32x4 ts = red[0][0][L] + red[0][1][L] + red[0][2][L] + red[0][3][L];
    f32x4 t2 = red[1][0][L] + red[1][1][L] + red[1][2][L] + red[1][3][L];
    atomicAdd(&sum[4 * L + 0], ts[0]);
    atomicAdd(&sum[4 * L + 1], ts[1]);
    atomicAdd(&sum[4 * L + 2], ts[2]);
    atomicAdd(&sum[4 * L + 3], ts[3]);
    atomicAdd(&sumsq[4 * L + 0], t2[0]);
    atomicAdd(&sumsq[4 * L + 1], t2[1]);
    atomicAdd(&sumsq[4 * L + 2], t2[2]);
    atomicAdd(&sumsq[4 * L + 3], t2[3]);
  }
}

__global__ void bn_final_kernel(const float* __restrict__ stats,
                                const float* __restrict__ gamma,
                                const float* __restrict__ beta,
                                float* __restrict__ sb) {
  const int c = threadIdx.x;
  for (int t = 0; t < 2; ++t) {
    const float mu  = stats[t * 512 + c] * (1.f / kN);
    const float var = stats[t * 512 + 256 + c] * (1.f / kN) - mu * mu;
    const float sc  = gamma[c] * rsqrtf(var + kBnEps);
    sb[t * 512 + c]       = sc;
    sb[t * 512 + 256 + c] = beta[c] - mu * sc;
  }
}

// ------------- edge classifier: sigmoid(<z_req[i], z_code[j]>), BN fused -------------
__global__ __launch_bounds__(256) void classify_kernel(
    const float* __restrict__ zr, const float* __restrict__ zc,
    const int* __restrict__ ei, const int* __restrict__ ej,
    const float* __restrict__ sb, float* __restrict__ y, int EL) {
  const int e = blockIdx.x * 4 + (threadIdx.x >> 6);
  if (e >= EL) return;
  const int L = threadIdx.x & 63;
  const int i = ei[e], j = ej[e];
  const float4 a  = *(const float4*)&zr[(size_t)i * kC + 4 * L];
  const float4 b  = *(const float4*)&zc[(size_t)j * kC + 4 * L];
  const float4 sr = *(const float4*)&sb[4 * L];
  const float4 br = *(const float4*)&sb[256 + 4 * L];
  const float4 sc = *(const float4*)&sb[512 + 4 * L];
  const float4 bc = *(const float4*)&sb[768 + 4 * L];
  float p = (a.x * sr.x + br.x) * (b.x * sc.x + bc.x) +
            (a.y * sr.y + br.y) * (b.y * sc.y + bc.y) +
            (a.z * sr.z + br.z) * (b.z * sc.z + bc.z) +
            (a.w * sr.w + br.w) * (b.w * sc.w + bc.w);
  for (int m = 1; m < 64; m <<= 1) p += __shfl_xor(p, m);
  if (L == 0) y[e] = 1.f / (1.f + __expf(-p));
}

}  // namespace

extern "C" void kernel_launch(void* const* d_in, const int* in_sizes, int n_in,
                              void* d_out, int out_size, void* d_ws, size_t ws_size,
                              hipStream_t stream) {
  (void)in_sizes; (void)n_in; (void)out_size; (void)ws_size;
  const float* x_req      = (const float*)d_in[0];
  const float* x_code     = (const float*)d_in[1];
  const int*   ei_rc      = (const int*)d_in[2];   // [src(E) | dst(E)] req -> code
  const int*   ei_cr      = (const int*)d_in[3];   // [src(E) | dst(E)] code -> req
  const int*   el         = (const int*)d_in[4];   // [req(EL) | code(EL)]
  const float* W_req      = (const float*)d_in[5];
  const float* b_req      = (const float*)d_in[6];
  const float* W_code     = (const float*)d_in[7];
  const float* b_code     = (const float*)d_in[8];
  const float* att_src_rc = (const float*)d_in[9];
  const float* att_dst_rc = (const float*)d_in[10];
  const float* att_src_cr = (const float*)d_in[11];
  const float* att_dst_cr = (const float*)d_in[12];
  // d_in[13..15] = k_W, k_b, q : semantic attn over ONE metapath == identity -> unused
  const float* gamma      = (const float*)d_in[16];
  const float* beta       = (const float*)d_in[17];
  float* y = (float*)d_out;

  // ---- workspace (~325 MB peak) ----
  char* p = (char*)d_ws;
  auto alloc = [&](size_t bytes) {
    char* r = p;
    p += (bytes + 1023) & ~(size_t)1023;
    return r;
  };
  // X split-bf16 region, reused per node type; reused again as out_code after GEMMs
  unsigned short* Xhi = (unsigned short*)alloc((size_t)kNpad * kC * 2);  // 51.25 MB
  unsigned short* Xlo = (unsigned short*)alloc((size_t)kNpad * kC * 2);  // 51.25 MB
  float* out_code = (float*)Xhi;  // alias: X dead after both GEMMs (needs 102.4 MB)
  _Float16* h_req  = (_Float16*)alloc((size_t)kN * kC * 2);  // 51.2 MB
  _Float16* h_code = (_Float16*)alloc((size_t)kN * kC * 2);  // 51.2 MB
  float* out_req   = (float*)alloc((size_t)kN * kC * 4);     // 102.4 MB
  unsigned short* Whi_r = (unsigned short*)alloc((size_t)kC * kC * 2);
  unsigned short* Wlo_r = (unsigned short*)alloc((size_t)kC * kC * 2);
  unsigned short* Whi_c = (unsigned short*)alloc((size_t)kC * kC * 2);
  unsigned short* Wlo_c = (unsigned short*)alloc((size_t)kC * kC * 2);
  float* a_src_rc = (float*)alloc((size_t)kN * kH * 4);
  float* a_dst_rc = (float*)alloc((size_t)kN * kH * 4);
  float* a_src_cr = (float*)alloc((size_t)kN * kH * 4);
  float* a_dst_cr = (float*)alloc((size_t)kN * kH * 4);
  int* cnt_rc  = (int*)alloc((size_t)kN * 4);
  int* off_rc  = (int*)alloc((size_t)kN * 4);
  int* cur_rc  = (int*)alloc((size_t)kN * 4);
  int* perm_rc = (int*)alloc((size_t)kE * 4);
  int* cnt_cr  = (int*)alloc((size_t)kN * 4);
  int* off_cr  = (int*)alloc((size_t)kN * 4);
  int* cur_cr  = (int*)alloc((size_t)kN * 4);
  int* perm_cr = (int*)alloc((size_t)kE * 4);
  int*   part  = (int*)alloc(512 * 4);
  float* stats = (float*)alloc(1024 * 4);
  float* sb    = (float*)alloc(1024 * 4);

  const int nScanB = (kN + 255) / 256;  // 391
  const int nX4    = kN * kC / 4;       // 6.4M float4
  const int nW4    = kC * kC / 4;       // 16384 float4

  zero_kernel<<<nScanB, 256, 0, stream>>>(cnt_rc, kN);
  zero_kernel<<<nScanB, 256, 0, stream>>>(cnt_cr, kN);
  zero_kernel<<<4, 256, 0, stream>>>((int*)stats, 1024);

  // weight conversion (tiny)
  cvt_kernel<<<(nW4 + 255) / 256, 256, 0, stream>>>(W_req, Whi_r, Wlo_r, nW4);
  cvt_kernel<<<(nW4 + 255) / 256, 256, 0, stream>>>(W_code, Whi_c, Wlo_c, nW4);

  // projections, per node type (X region reused)
  dim3 ggrid(kC / 128, kNpad / 128);
  cvt_kernel<<<(nX4 + 255) / 256, 256, 0, stream>>>(x_req, Xhi, Xlo, nX4);
  gemm_kernel<<<ggrid, 256, 0, stream>>>(Xhi, Xlo, Whi_r, Wlo_r, b_req, h_req, kN);
  cvt_kernel<<<(nX4 + 255) / 256, 256, 0, stream>>>(x_code, Xhi, Xlo, nX4);
  gemm_kernel<<<ggrid, 256, 0, stream>>>(Xhi, Xlo, Whi_c, Wlo_c, b_code, h_code, kN);

  // attention scalars: req is src in rc / dst in cr; code is src in cr / dst in rc
  avec_kernel<<<(kN + 3) / 4, 256, 0, stream>>>(h_req, att_src_rc, att_dst_cr,
                                                a_src_rc, a_dst_cr, kN);
  avec_kernel<<<(kN + 3) / 4, 256, 0, stream>>>(h_code, att_src_cr, att_dst_rc,
                                                a_src_cr, a_dst_rc, kN);

  // CSR build (dst-sorted edge permutation per direction)
  const int* dst_rc = ei_rc + kE;
  const int* dst_cr = ei_cr + kE;
  count_kernel<<<(kE + 255) / 256, 256, 0, stream>>>(dst_rc, kE, cnt_rc);
  count_kernel<<<(kE + 255) / 256, 256, 0, stream>>>(dst_cr, kE, cnt_cr);
  scan1_kernel<<<nScanB, 256, 0, stream>>>(cnt_rc, kN, off_rc, part);
  scan2_kernel<<<1, 512, 0, stream>>>(part, nScanB);
  scan3_kernel<<<nScanB, 256, 0, stream>>>(off_rc, cur_rc, part, kN);
  scan1_kernel<<<nScanB, 256, 0, stream>>>(cnt_cr, kN, off_cr, part);
  scan2_kernel<<<1, 512, 0, stream>>>(part, nScanB);
  scan3_kernel<<<nScanB, 256, 0, stream>>>(off_cr, cur_cr, part, kN);
  scatter_kernel<<<(kE + 255) / 256, 256, 0, stream>>>(dst_rc, kE, cur_rc, perm_rc);
  scatter_kernel<<<(kE + 255) / 256, 256, 0, stream>>>(dst_cr, kE, cur_cr, perm_cr);

  // fused attention softmax + aggregation + relu
  // rc first (reads h_req, writes out_code over the dead X region)...
  aggregate_kernel<<<(kN + 3) / 4, 256, 0, stream>>>(
      h_req, a_src_rc, a_dst_rc, ei_rc, off_rc, cnt_rc, perm_rc, out_code, kN);
  // ...then cr (reads h_code, writes out_req)
  aggregate_kernel<<<(kN + 3) / 4, 256, 0, stream>>>(
      h_code, a_src_cr, a_dst_cr, ei_cr, off_cr, cnt_cr, perm_cr, out_req, kN);

  // BatchNorm (training-mode batch stats) folded into per-channel scale/bias
  bn_stats_kernel<<<kBnBlocks, 256, 0, stream>>>(out_req, kN, stats, stats + 256);
  bn_stats_kernel<<<kBnBlocks, 256, 0, stream>>>(out_code, kN, stats + 512, stats + 768);
  bn_final_kernel<<<1, 256, 0, stream>>>(stats, gamma, beta, sb);

  // edge dot-product classifier
  classify_kernel<<<(kEL + 3) / 4, 256, 0, stream>>>(
      out_req, out_code, el, el + kEL, sb, y, kEL);
}